// Round 5
// baseline (113.393 us; speedup 1.0000x reference)
//
#include <hip/hip_runtime.h>

#define NMS_TH 0.7

// ---------------------------------------------------------------------------
// Kernel A: per-box fp64 corners (CCW) + fp64 areas + fp32 AABB + fp32 area.
// ---------------------------------------------------------------------------
__global__ void corners_kernel(const float* __restrict__ boxes,
                               double* __restrict__ cor,    // N*8
                               double* __restrict__ areas,  // N
                               float* __restrict__ aabb,    // 5*N
                               int N) {
    int i = blockIdx.x * blockDim.x + threadIdx.x;
    if (i >= N) return;
    double xc = boxes[i * 5 + 0];
    double yc = boxes[i * 5 + 1];
    double w  = boxes[i * 5 + 2];
    double h  = boxes[i * 5 + 3];
    double t  = boxes[i * 5 + 4];
    double th = t * 0.017453292519943295;  // pi/180
    double c = cos(th), s = sin(th);
    const double lx[4] = {0.5, -0.5, -0.5, 0.5};
    const double ly[4] = {0.5, 0.5, -0.5, -0.5};
    double xmn = 1e30, xmx = -1e30, ymn = 1e30, ymx = -1e30;
#pragma unroll
    for (int k = 0; k < 4; ++k) {
        double x = xc + lx[k] * w * c - ly[k] * h * s;
        double y = yc + lx[k] * w * s + ly[k] * h * c;
        cor[i * 8 + k * 2 + 0] = x;
        cor[i * 8 + k * 2 + 1] = y;
        xmn = fmin(xmn, x); xmx = fmax(xmx, x);
        ymn = fmin(ymn, y); ymx = fmax(ymx, y);
    }
    areas[i] = w * h;
    aabb[0 * N + i] = (float)xmn;
    aabb[1 * N + i] = (float)xmx;
    aabb[2 * N + i] = (float)ymn;
    aabb[3 * N + i] = (float)ymx;
    aabb[4 * N + i] = (float)(w * h);
}

// ---------------------------------------------------------------------------
// Exact convex-quad intersection area via Green's theorem (fp64, static).
// ---------------------------------------------------------------------------
__device__ __forceinline__ double clip_sum(const double* __restrict__ px,
                                           const double* __restrict__ py,
                                           const double* __restrict__ qx,
                                           const double* __restrict__ qy) {
    double acc = 0.0;
#pragma unroll
    for (int e = 0; e < 4; ++e) {
        double x0 = px[e], y0 = py[e];
        double x1 = px[(e + 1) & 3], y1 = py[(e + 1) & 3];
        double dx = x1 - x0, dy = y1 - y0;
        double t0 = 0.0, t1 = 1.0;
        bool empty = false;
#pragma unroll
        for (int f = 0; f < 4; ++f) {
            double ex0 = qx[f], ey0 = qy[f];
            double ex1 = qx[(f + 1) & 3], ey1 = qy[(f + 1) & 3];
            double edx = ex1 - ex0, edy = ey1 - ey0;
            double f0 = edx * (y0 - ey0) - edy * (x0 - ex0);
            double f1 = edx * (y1 - ey0) - edy * (x1 - ex0);
            double df = f1 - f0;
            if (df > 0.0) {
                t0 = fmax(t0, -f0 / df);
            } else if (df < 0.0) {
                t1 = fmin(t1, -f0 / df);
            } else if (f0 < 0.0) {
                empty = true;
            }
        }
        if (!empty && t0 < t1) {
            double ax = x0 + t0 * dx, ay = y0 + t0 * dy;
            double bx = x0 + t1 * dx, by = y0 + t1 * dy;
            acc += ax * by - bx * ay;
        }
    }
    return acc;
}

// i-side corners/area pre-hoisted into registers by the caller.
__device__ __forceinline__ bool exact_suppress2(const double px[4],
                                                const double py[4], double ai,
                                                const double* __restrict__ cor,
                                                const double* __restrict__ areas,
                                                int j) {
    double qx[4], qy[4];
#pragma unroll
    for (int k = 0; k < 4; ++k) {
        qx[k] = cor[j * 8 + k * 2 + 0];
        qy[k] = cor[j * 8 + k * 2 + 1];
    }
    double inter = 0.5 * (clip_sum(px, py, qx, qy) + clip_sum(qx, qy, px, py));
    inter = fmax(inter, 0.0);
    double uni = ai + areas[j] - inter;
    double iou = inter / fmax(uni, 1e-8);
    return iou > NMS_TH;
}

// ---------------------------------------------------------------------------
// Kernel B (fused): block = row i, 256 threads.
// Phase 1: fp32 AABB upper-bound filter, j-loop starting at the 256-aligned
//   block containing i+1 (halves the O(N^2) scan).  Candidate iff
//   1.699*min(AABB_inter, a_i, a_j) >= 0.699*(a_i+a_j)  — guard band 1e-3
//   vs 0.7, safe vs exact fp64.  LDS-compacted candidate list.
// Phase 2: exact fp64 clip on the dense list; 32-bit LDS atomicOr bits.
// Epilogue: store 32 mask words + per-row suppressor flag byte.
// ---------------------------------------------------------------------------
__global__ __launch_bounds__(256) void iou_fused_kernel(
    const float* __restrict__ aabb, const double* __restrict__ cor,
    const double* __restrict__ areas, unsigned long long* __restrict__ mask,
    unsigned char* __restrict__ flags, int N, int words) {
    __shared__ unsigned short cand[2048];
    __shared__ unsigned int lmask32[64];
    __shared__ int cnt;
    __shared__ int supflag;

    int i = blockIdx.x;
    int t = threadIdx.x;
    if (t == 0) { cnt = 0; supflag = 0; }
    if (t < 64) lmask32[t] = 0u;
    __syncthreads();

    float ixmn = aabb[0 * N + i], ixmx = aabb[1 * N + i];
    float iymn = aabb[2 * N + i], iymx = aabb[3 * N + i];
    float iaf = aabb[4 * N + i];

    int j0 = (((i + 1) >> 8) << 8) + t;  // first 256-block containing i+1
    for (int j = j0; j < N; j += 256) {
        if (j <= i) continue;
        float iw = fminf(ixmx, aabb[1 * N + j]) - fmaxf(ixmn, aabb[0 * N + j]);
        float ih = fminf(iymx, aabb[3 * N + j]) - fmaxf(iymn, aabb[2 * N + j]);
        if (iw > 0.0f && ih > 0.0f) {
            float jaf = aabb[4 * N + j];
            float ub = fminf(iw * ih, fminf(iaf, jaf));
            if (1.699f * ub >= 0.699f * (iaf + jaf)) {
                int p = atomicAdd(&cnt, 1);
                cand[p] = (unsigned short)j;
            }
        }
    }
    __syncthreads();

    int n = cnt;
    if (n) {
        double px[4], py[4];
#pragma unroll
        for (int k = 0; k < 4; ++k) {
            px[k] = cor[i * 8 + k * 2 + 0];
            py[k] = cor[i * 8 + k * 2 + 1];
        }
        double ai = areas[i];
        for (int k = t; k < n; k += 256) {
            int j = (int)cand[k];
            if (exact_suppress2(px, py, ai, cor, areas, j)) {
                atomicOr(&lmask32[j >> 5], 1u << (j & 31));
                supflag = 1;  // benign race
            }
        }
    }
    __syncthreads();

    if (t < words) {
        unsigned long long wv = ((unsigned long long)lmask32[2 * t + 1] << 32) |
                                (unsigned long long)lmask32[2 * t];
        mask[(size_t)i * words + t] = wv;
    }
    if (t == 0) flags[i] = (unsigned char)(supflag != 0);
}

// ---------------------------------------------------------------------------
// Kernel C: sparse greedy sweep, one wave.  Lane L owns 'removed' word L.
// Dense 32-chunk walk with diag prefetched one chunk ahead (off the serial
// chain).  Resolve loop picks only currently-unsuppressed suppressor rows
// (lowest such row is provably kept) -> exactly one shfl per KEPT suppressor
// row.  Kept rows' full mask rows OR'd in via a 2-deep load pipeline.
// ---------------------------------------------------------------------------
__global__ __launch_bounds__(64, 1) void greedy_kernel(
    const unsigned long long* __restrict__ mask,
    const unsigned char* __restrict__ flags, int* __restrict__ out,
    int N, int words, int topn) {
    int lane = threadIdx.x;
    int wl = lane < words ? lane : (words - 1);  // clamped lane->word addr
    unsigned long long removed = 0ULL;

    // per-chunk suppressor-row bitmaps: lane c holds chunk c's bitmap
    unsigned long long nzw = 0ULL;
    for (int c = 0; c < words; ++c) {
        int r = c * 64 + lane;
        unsigned char f = (r < N) ? flags[r] : (unsigned char)0;
        unsigned long long bal = __ballot(f != 0);
        if (lane == c) nzw = bal;
    }

    // prefetch chunk 0's diagonal block (lane L = row L's word 0)
    unsigned long long diag_next =
        (lane < N) ? mask[(size_t)lane * words + 0] : 0ULL;

    for (int c = 0; c < words; ++c) {
        unsigned long long diag = diag_next;
        int cn = c + 1;
        int rn = cn * 64 + lane;
        diag_next =
            (cn < words && rn < N) ? mask[(size_t)rn * words + cn] : 0ULL;

        unsigned long long bits = __shfl(nzw, c);
        if (!bits) continue;
        int base = c * 64;

        // resolve: pick lowest unsuppressed suppressor row; it is kept.
        unsigned long long dm = __shfl(removed, c);
        unsigned long long K = 0ULL;
        unsigned long long rem_rows = bits;
        for (;;) {
            unsigned long long bb = rem_rows & ~dm;
            if (!bb) break;
            int b = __ffsll(bb) - 1;
            rem_rows &= ~(1ULL << b);
            K |= 1ULL << b;
            dm |= __shfl(diag, b);
        }

        // apply kept suppressor rows (2-deep pipelined row loads)
        unsigned long long ap = bits & K;
        if (ap) {
            int b0 = __ffsll(ap) - 1;
            ap &= ap - 1ULL;
            unsigned long long v0 = mask[(size_t)(base + b0) * words + wl];
            while (ap) {
                int b1 = __ffsll(ap) - 1;
                ap &= ap - 1ULL;
                unsigned long long v1 = mask[(size_t)(base + b1) * words + wl];
                removed |= v0;
                v0 = v1;
            }
            removed |= v0;
        }
    }

    // keep mask per lane-owned word, clipped to N bits
    unsigned long long keepw = 0ULL;
    if (lane < words) {
        keepw = ~removed;
        int base = lane * 64;
        int valid = N - base;
        if (valid <= 0)
            keepw = 0ULL;
        else if (valid < 64)
            keepw &= ((1ULL << valid) - 1ULL);
    }

    // exclusive prefix of popcounts across lanes
    int pc = __popcll(keepw);
    int scan = pc;
#pragma unroll
    for (int off = 1; off < 64; off <<= 1) {
        int v = __shfl_up(scan, off);
        if (lane >= off) scan += v;
    }
    int base_out = scan - pc;
    int total = __shfl(scan, words - 1);

    // emit kept indices
    if (lane < words) {
        int pos = base_out;
        unsigned long long w = keepw;
        while (w) {
            int b = __ffsll(w) - 1;
            w &= w - 1ULL;
            if (pos < topn) out[pos] = lane * 64 + b;
            ++pos;
        }
    }
    // pad tail with -1
    for (int k = (total < topn ? total : topn) + lane; k < topn; k += 64)
        out[k] = -1;
}

// ---------------------------------------------------------------------------
extern "C" void kernel_launch(void* const* d_in, const int* in_sizes, int n_in,
                              void* d_out, int out_size, void* d_ws,
                              size_t ws_size, hipStream_t stream) {
    const float* boxes = (const float*)d_in[0];
    int N = in_sizes[0] / 5;      // 2000
    int words = (N + 63) / 64;    // 32
    int topn = out_size;          // 1000

    char* ws = (char*)d_ws;
    size_t off = 0;
    double* cor = (double*)(ws + off);   off += (size_t)N * 8 * 8;
    double* areas = (double*)(ws + off); off += (size_t)N * 8;
    unsigned long long* mask =
        (unsigned long long*)(ws + off); off += (size_t)N * words * 8;
    float* aabb = (float*)(ws + off);    off += (size_t)N * 5 * 4;
    unsigned char* flags = (unsigned char*)(ws + off); off += (size_t)N;

    corners_kernel<<<(N + 255) / 256, 256, 0, stream>>>(boxes, cor, areas,
                                                        aabb, N);
    iou_fused_kernel<<<N, 256, 0, stream>>>(aabb, cor, areas, mask, flags, N,
                                            words);
    greedy_kernel<<<1, 64, 0, stream>>>(mask, flags, (int*)d_out, N, words,
                                        topn);
}

// Round 6
// 97.716 us; speedup vs baseline: 1.1604x; 1.1604x over previous
//
#include <hip/hip_runtime.h>

#define NMS_TH 0.7

__device__ __forceinline__ unsigned long long rfl64(unsigned long long x) {
    unsigned int lo = __builtin_amdgcn_readfirstlane((unsigned int)x);
    unsigned int hi = __builtin_amdgcn_readfirstlane((unsigned int)(x >> 32));
    return ((unsigned long long)hi << 32) | lo;
}
__device__ __forceinline__ unsigned long long readlane64(unsigned long long x,
                                                         int l) {
    unsigned int lo = __builtin_amdgcn_readlane((unsigned int)x, l);
    unsigned int hi = __builtin_amdgcn_readlane((unsigned int)(x >> 32), l);
    return ((unsigned long long)hi << 32) | lo;
}

// ---------------------------------------------------------------------------
// Kernel A: per-box fp64 corners (CCW) + fp64 areas + fp32 AABB + fp32 area.
// ---------------------------------------------------------------------------
__global__ void corners_kernel(const float* __restrict__ boxes,
                               double* __restrict__ cor,    // N*8
                               double* __restrict__ areas,  // N
                               float* __restrict__ aabb,    // 5*N
                               int N) {
    int i = blockIdx.x * blockDim.x + threadIdx.x;
    if (i >= N) return;
    double xc = boxes[i * 5 + 0];
    double yc = boxes[i * 5 + 1];
    double w  = boxes[i * 5 + 2];
    double h  = boxes[i * 5 + 3];
    double t  = boxes[i * 5 + 4];
    double th = t * 0.017453292519943295;  // pi/180
    double c = cos(th), s = sin(th);
    const double lx[4] = {0.5, -0.5, -0.5, 0.5};
    const double ly[4] = {0.5, 0.5, -0.5, -0.5};
    double xmn = 1e30, xmx = -1e30, ymn = 1e30, ymx = -1e30;
#pragma unroll
    for (int k = 0; k < 4; ++k) {
        double x = xc + lx[k] * w * c - ly[k] * h * s;
        double y = yc + lx[k] * w * s + ly[k] * h * c;
        cor[i * 8 + k * 2 + 0] = x;
        cor[i * 8 + k * 2 + 1] = y;
        xmn = fmin(xmn, x); xmx = fmax(xmx, x);
        ymn = fmin(ymn, y); ymx = fmax(ymx, y);
    }
    areas[i] = w * h;
    aabb[0 * N + i] = (float)xmn;
    aabb[1 * N + i] = (float)xmx;
    aabb[2 * N + i] = (float)ymn;
    aabb[3 * N + i] = (float)ymx;
    aabb[4 * N + i] = (float)(w * h);
}

// ---------------------------------------------------------------------------
// Exact convex-quad intersection area via Green's theorem (fp64, static).
// ---------------------------------------------------------------------------
__device__ __forceinline__ double clip_sum(const double* __restrict__ px,
                                           const double* __restrict__ py,
                                           const double* __restrict__ qx,
                                           const double* __restrict__ qy) {
    double acc = 0.0;
#pragma unroll
    for (int e = 0; e < 4; ++e) {
        double x0 = px[e], y0 = py[e];
        double x1 = px[(e + 1) & 3], y1 = py[(e + 1) & 3];
        double dx = x1 - x0, dy = y1 - y0;
        double t0 = 0.0, t1 = 1.0;
        bool empty = false;
#pragma unroll
        for (int f = 0; f < 4; ++f) {
            double ex0 = qx[f], ey0 = qy[f];
            double ex1 = qx[(f + 1) & 3], ey1 = qy[(f + 1) & 3];
            double edx = ex1 - ex0, edy = ey1 - ey0;
            double f0 = edx * (y0 - ey0) - edy * (x0 - ex0);
            double f1 = edx * (y1 - ey0) - edy * (x1 - ex0);
            double df = f1 - f0;
            if (df > 0.0) {
                t0 = fmax(t0, -f0 / df);
            } else if (df < 0.0) {
                t1 = fmin(t1, -f0 / df);
            } else if (f0 < 0.0) {
                empty = true;
            }
        }
        if (!empty && t0 < t1) {
            double ax = x0 + t0 * dx, ay = y0 + t0 * dy;
            double bx = x0 + t1 * dx, by = y0 + t1 * dy;
            acc += ax * by - bx * ay;
        }
    }
    return acc;
}

__device__ __forceinline__ bool exact_suppress2(const double px[4],
                                                const double py[4], double ai,
                                                const double* __restrict__ cor,
                                                const double* __restrict__ areas,
                                                int j) {
    double qx[4], qy[4];
#pragma unroll
    for (int k = 0; k < 4; ++k) {
        qx[k] = cor[j * 8 + k * 2 + 0];
        qy[k] = cor[j * 8 + k * 2 + 1];
    }
    double inter = 0.5 * (clip_sum(px, py, qx, qy) + clip_sum(qx, qy, px, py));
    inter = fmax(inter, 0.0);
    double uni = ai + areas[j] - inter;
    double iou = inter / fmax(uni, 1e-8);
    return iou > NMS_TH;
}

// ---------------------------------------------------------------------------
// Kernel B (fused): block = row i, 256 threads.  fp32 AABB filter (exact-safe
// guard band) -> LDS candidate list -> exact fp64 clip -> LDS mask bits ->
// one global row store + suppressor flag byte.  No global atomics.
// ---------------------------------------------------------------------------
__global__ __launch_bounds__(256) void iou_fused_kernel(
    const float* __restrict__ aabb, const double* __restrict__ cor,
    const double* __restrict__ areas, unsigned long long* __restrict__ mask,
    unsigned char* __restrict__ flags, int N, int words) {
    __shared__ unsigned short cand[2048];
    __shared__ unsigned int lmask32[64];
    __shared__ int cnt;
    __shared__ int supflag;

    int i = blockIdx.x;
    int t = threadIdx.x;
    if (t == 0) { cnt = 0; supflag = 0; }
    if (t < 64) lmask32[t] = 0u;
    __syncthreads();

    float ixmn = aabb[0 * N + i], ixmx = aabb[1 * N + i];
    float iymn = aabb[2 * N + i], iymx = aabb[3 * N + i];
    float iaf = aabb[4 * N + i];

    int j0 = (((i + 1) >> 8) << 8) + t;  // first 256-block containing i+1
    for (int j = j0; j < N; j += 256) {
        if (j <= i) continue;
        float iw = fminf(ixmx, aabb[1 * N + j]) - fmaxf(ixmn, aabb[0 * N + j]);
        float ih = fminf(iymx, aabb[3 * N + j]) - fmaxf(iymn, aabb[2 * N + j]);
        if (iw > 0.0f && ih > 0.0f) {
            float jaf = aabb[4 * N + j];
            float ub = fminf(iw * ih, fminf(iaf, jaf));
            if (1.699f * ub >= 0.699f * (iaf + jaf)) {
                int p = atomicAdd(&cnt, 1);
                cand[p] = (unsigned short)j;
            }
        }
    }
    __syncthreads();

    int n = cnt;
    if (n) {
        double px[4], py[4];
#pragma unroll
        for (int k = 0; k < 4; ++k) {
            px[k] = cor[i * 8 + k * 2 + 0];
            py[k] = cor[i * 8 + k * 2 + 1];
        }
        double ai = areas[i];
        for (int k = t; k < n; k += 256) {
            int j = (int)cand[k];
            if (exact_suppress2(px, py, ai, cor, areas, j)) {
                atomicOr(&lmask32[j >> 5], 1u << (j & 31));
                supflag = 1;  // benign race
            }
        }
    }
    __syncthreads();

    if (t < words) {
        unsigned long long wv = ((unsigned long long)lmask32[2 * t + 1] << 32) |
                                (unsigned long long)lmask32[2 * t];
        mask[(size_t)i * words + t] = wv;
    }
    if (t == 0) flags[i] = (unsigned char)(supflag != 0);
}

// ---------------------------------------------------------------------------
// Kernel C: sparse greedy sweep v4, one wave.  Lane L owns 'removed' word
// L&31.  Setup: flags via 8 coalesced u32 loads/lane, per-chunk suppressor
// bitmaps built from registers (shfl+ballot).  Walk only ACTIVE chunks; diag
// prefetched for the next active chunk.  Resolve forced onto SALU/readlane
// (all masks wave-uniform scalars).  Apply: 8-deep software pipeline (two
// 4-wide load batches in flight).
// ---------------------------------------------------------------------------
__global__ __launch_bounds__(64, 1) void greedy_kernel(
    const unsigned long long* __restrict__ mask,
    const unsigned char* __restrict__ flags, int* __restrict__ out,
    int N, int words, int topn) {
    int lane = threadIdx.x;
    int wl = lane & 31;  // owned word (lanes >=32 duplicate; words<=32)
    unsigned long long removed = 0ULL;

    // --- setup: coalesced flags load (u32 x8 per lane covers 2048 rows) ---
    unsigned int fvec[8];
    const unsigned int* f32 = (const unsigned int*)flags;
    int nw32 = (N + 3) >> 2;
#pragma unroll
    for (int k = 0; k < 8; ++k) {
        int wi = k * 64 + lane;
        fvec[k] = (wi < nw32) ? f32[wi] : 0u;
    }
    // per-chunk suppressor bitmaps: lane c holds chunk c's bitmap
    unsigned long long nzw = 0ULL;
#pragma unroll
    for (int c = 0; c < 32; ++c) {
        if (c < words) {
            unsigned int v =
                __shfl(fvec[c >> 2], ((c & 3) << 4) | (lane >> 2));
            unsigned int byte = (v >> ((lane & 3) * 8)) & 0xffu;
            int r = c * 64 + lane;
            unsigned long long bal = __ballot(byte != 0u && r < N);
            if (lane == c) nzw = bal;
        }
    }
    unsigned int am =
        __builtin_amdgcn_readfirstlane((unsigned int)__ballot(nzw != 0ULL));

    // prologue: prefetch first active chunk's diag
    unsigned long long diag_nxt = 0ULL;
    if (am) {
        int c0 = __ffs(am) - 1;
        int r0 = c0 * 64 + lane;
        diag_nxt = (r0 < N) ? mask[(size_t)r0 * words + c0] : 0ULL;
    }

    unsigned int amw = am;
    while (amw) {
        int c = __ffs(amw) - 1;
        amw &= amw - 1;
        unsigned long long diag = diag_nxt;
        if (amw) {  // issue next ACTIVE chunk's diag (lands during resolve+apply)
            int cn = __ffs(amw) - 1;
            int rn = cn * 64 + lane;
            diag_nxt = (rn < N) ? mask[(size_t)rn * words + cn] : 0ULL;
        } else {
            diag_nxt = 0ULL;
        }
        unsigned long long bits = rfl64(__shfl(nzw, c));
        int base = c * 64;

        // resolve (wave-uniform scalar chain; diag access = v_readlane)
        unsigned long long dm = readlane64(removed, c);
        unsigned long long K = 0ULL;
        unsigned long long rem_rows = bits;
        for (;;) {
            unsigned long long bb = rem_rows & ~dm;
            if (!bb) break;
            int b = __builtin_amdgcn_readfirstlane(__ffsll(bb) - 1);
            rem_rows &= ~(1ULL << b);
            K |= 1ULL << b;
            dm |= readlane64(diag, b);
        }

        // apply kept suppressor rows: 8-deep pipeline (2x 4-wide batches)
        unsigned long long ap = K;
        unsigned long long p0 = 0, p1 = 0, p2 = 0, p3 = 0;
        int have = 0;
        while (ap) {
            unsigned long long l0 = 0, l1 = 0, l2 = 0, l3 = 0;
            int b0 = __builtin_amdgcn_readfirstlane(__ffsll(ap) - 1);
            ap &= ap - 1ULL;
            l0 = mask[(size_t)(base + b0) * words + wl];
            if (ap) {
                int b1 = __builtin_amdgcn_readfirstlane(__ffsll(ap) - 1);
                ap &= ap - 1ULL;
                l1 = mask[(size_t)(base + b1) * words + wl];
            }
            if (ap) {
                int b2 = __builtin_amdgcn_readfirstlane(__ffsll(ap) - 1);
                ap &= ap - 1ULL;
                l2 = mask[(size_t)(base + b2) * words + wl];
            }
            if (ap) {
                int b3 = __builtin_amdgcn_readfirstlane(__ffsll(ap) - 1);
                ap &= ap - 1ULL;
                l3 = mask[(size_t)(base + b3) * words + wl];
            }
            if (have) removed |= (p0 | p1) | (p2 | p3);
            p0 = l0; p1 = l1; p2 = l2; p3 = l3;
            have = 1;
        }
        if (have) removed |= (p0 | p1) | (p2 | p3);
    }

    // keep mask per lane-owned word, clipped to N bits
    unsigned long long keepw = 0ULL;
    if (lane < words) {
        keepw = ~removed;
        int base = lane * 64;
        int valid = N - base;
        if (valid <= 0)
            keepw = 0ULL;
        else if (valid < 64)
            keepw &= ((1ULL << valid) - 1ULL);
    }

    // exclusive prefix of popcounts across lanes
    int pc = __popcll(keepw);
    int scan = pc;
#pragma unroll
    for (int off = 1; off < 64; off <<= 1) {
        int v = __shfl_up(scan, off);
        if (lane >= off) scan += v;
    }
    int base_out = scan - pc;
    int total = __shfl(scan, words - 1);

    // emit kept indices
    if (lane < words) {
        int pos = base_out;
        unsigned long long w = keepw;
        while (w) {
            int b = __ffsll(w) - 1;
            w &= w - 1ULL;
            if (pos < topn) out[pos] = lane * 64 + b;
            ++pos;
        }
    }
    // pad tail with -1
    for (int k = (total < topn ? total : topn) + lane; k < topn; k += 64)
        out[k] = -1;
}

// ---------------------------------------------------------------------------
extern "C" void kernel_launch(void* const* d_in, const int* in_sizes, int n_in,
                              void* d_out, int out_size, void* d_ws,
                              size_t ws_size, hipStream_t stream) {
    const float* boxes = (const float*)d_in[0];
    int N = in_sizes[0] / 5;      // 2000
    int words = (N + 63) / 64;    // 32
    int topn = out_size;          // 1000

    char* ws = (char*)d_ws;
    size_t off = 0;
    double* cor = (double*)(ws + off);   off += (size_t)N * 8 * 8;
    double* areas = (double*)(ws + off); off += (size_t)N * 8;
    unsigned long long* mask =
        (unsigned long long*)(ws + off); off += (size_t)N * words * 8;
    float* aabb = (float*)(ws + off);    off += (size_t)N * 5 * 4;
    unsigned char* flags = (unsigned char*)(ws + off); off += (size_t)N;

    corners_kernel<<<(N + 255) / 256, 256, 0, stream>>>(boxes, cor, areas,
                                                        aabb, N);
    iou_fused_kernel<<<N, 256, 0, stream>>>(aabb, cor, areas, mask, flags, N,
                                            words);
    greedy_kernel<<<1, 64, 0, stream>>>(mask, flags, (int*)d_out, N, words,
                                        topn);
}

// Round 7
// 93.055 us; speedup vs baseline: 1.2186x; 1.0501x over previous
//
#include <hip/hip_runtime.h>

#define NMS_TH 0.7

__device__ __forceinline__ unsigned long long rfl64(unsigned long long x) {
    unsigned int lo = __builtin_amdgcn_readfirstlane((unsigned int)x);
    unsigned int hi = __builtin_amdgcn_readfirstlane((unsigned int)(x >> 32));
    return ((unsigned long long)hi << 32) | lo;
}
__device__ __forceinline__ unsigned long long readlane64(unsigned long long x,
                                                         int l) {
    unsigned int lo = __builtin_amdgcn_readlane((unsigned int)x, l);
    unsigned int hi = __builtin_amdgcn_readlane((unsigned int)(x >> 32), l);
    return ((unsigned long long)hi << 32) | lo;
}

// ---------------------------------------------------------------------------
// Kernel A: per-box fp64 corners (CCW) + fp64 areas + fp32 AABB + fp32 area.
// ---------------------------------------------------------------------------
__global__ void corners_kernel(const float* __restrict__ boxes,
                               double* __restrict__ cor,    // N*8
                               double* __restrict__ areas,  // N
                               float* __restrict__ aabb,    // 5*N
                               int N) {
    int i = blockIdx.x * blockDim.x + threadIdx.x;
    if (i >= N) return;
    double xc = boxes[i * 5 + 0];
    double yc = boxes[i * 5 + 1];
    double w  = boxes[i * 5 + 2];
    double h  = boxes[i * 5 + 3];
    double t  = boxes[i * 5 + 4];
    double th = t * 0.017453292519943295;  // pi/180
    double c = cos(th), s = sin(th);
    const double lx[4] = {0.5, -0.5, -0.5, 0.5};
    const double ly[4] = {0.5, 0.5, -0.5, -0.5};
    double xmn = 1e30, xmx = -1e30, ymn = 1e30, ymx = -1e30;
#pragma unroll
    for (int k = 0; k < 4; ++k) {
        double x = xc + lx[k] * w * c - ly[k] * h * s;
        double y = yc + lx[k] * w * s + ly[k] * h * c;
        cor[i * 8 + k * 2 + 0] = x;
        cor[i * 8 + k * 2 + 1] = y;
        xmn = fmin(xmn, x); xmx = fmax(xmx, x);
        ymn = fmin(ymn, y); ymx = fmax(ymx, y);
    }
    areas[i] = w * h;
    aabb[0 * N + i] = (float)xmn;
    aabb[1 * N + i] = (float)xmx;
    aabb[2 * N + i] = (float)ymn;
    aabb[3 * N + i] = (float)ymx;
    aabb[4 * N + i] = (float)(w * h);
}

// ---------------------------------------------------------------------------
// Exact convex-quad intersection area via Green's theorem (fp64, static).
// ---------------------------------------------------------------------------
__device__ __forceinline__ double clip_sum(const double* __restrict__ px,
                                           const double* __restrict__ py,
                                           const double* __restrict__ qx,
                                           const double* __restrict__ qy) {
    double acc = 0.0;
#pragma unroll
    for (int e = 0; e < 4; ++e) {
        double x0 = px[e], y0 = py[e];
        double x1 = px[(e + 1) & 3], y1 = py[(e + 1) & 3];
        double dx = x1 - x0, dy = y1 - y0;
        double t0 = 0.0, t1 = 1.0;
        bool empty = false;
#pragma unroll
        for (int f = 0; f < 4; ++f) {
            double ex0 = qx[f], ey0 = qy[f];
            double ex1 = qx[(f + 1) & 3], ey1 = qy[(f + 1) & 3];
            double edx = ex1 - ex0, edy = ey1 - ey0;
            double f0 = edx * (y0 - ey0) - edy * (x0 - ex0);
            double f1 = edx * (y1 - ey0) - edy * (x1 - ex0);
            double df = f1 - f0;
            if (df > 0.0) {
                t0 = fmax(t0, -f0 / df);
            } else if (df < 0.0) {
                t1 = fmin(t1, -f0 / df);
            } else if (f0 < 0.0) {
                empty = true;
            }
        }
        if (!empty && t0 < t1) {
            double ax = x0 + t0 * dx, ay = y0 + t0 * dy;
            double bx = x0 + t1 * dx, by = y0 + t1 * dy;
            acc += ax * by - bx * ay;
        }
    }
    return acc;
}

__device__ __forceinline__ bool exact_suppress2(const double px[4],
                                                const double py[4], double ai,
                                                const double* __restrict__ cor,
                                                const double* __restrict__ areas,
                                                int j) {
    double qx[4], qy[4];
#pragma unroll
    for (int k = 0; k < 4; ++k) {
        qx[k] = cor[j * 8 + k * 2 + 0];
        qy[k] = cor[j * 8 + k * 2 + 1];
    }
    double inter = 0.5 * (clip_sum(px, py, qx, qy) + clip_sum(qx, qy, px, py));
    inter = fmax(inter, 0.0);
    double uni = ai + areas[j] - inter;
    double iou = inter / fmax(uni, 1e-8);
    return iou > NMS_TH;
}

// ---------------------------------------------------------------------------
// Kernel B (fused): block = row i, 256 threads.  fp32 AABB filter (exact-safe
// guard band) -> LDS candidate list -> exact fp64 clip -> LDS mask bits.
// Epilogue: store the 32-word mask row (stride fixed at 32) AND a 2xu64
// rowinfo record: [count:16 | t0:16 | t1:16 | t2:16], [t3:16|t4:16|t5:16|0]
// = first 6 suppressed targets inline (greedy's fast path; count>6 rows use
// the mask row).  No global atomics.
// ---------------------------------------------------------------------------
__global__ __launch_bounds__(256) void iou_fused_kernel(
    const float* __restrict__ aabb, const double* __restrict__ cor,
    const double* __restrict__ areas, unsigned long long* __restrict__ mask,
    unsigned long long* __restrict__ rowinfo, int N) {
    __shared__ unsigned short cand[2048];
    __shared__ unsigned int lmask32[64];
    __shared__ int cnt;

    int i = blockIdx.x;
    int t = threadIdx.x;
    if (t == 0) cnt = 0;
    if (t < 64) lmask32[t] = 0u;
    __syncthreads();

    float ixmn = aabb[0 * N + i], ixmx = aabb[1 * N + i];
    float iymn = aabb[2 * N + i], iymx = aabb[3 * N + i];
    float iaf = aabb[4 * N + i];

    int j0 = (((i + 1) >> 8) << 8) + t;  // first 256-block containing i+1
    for (int j = j0; j < N; j += 256) {
        if (j <= i) continue;
        float iw = fminf(ixmx, aabb[1 * N + j]) - fmaxf(ixmn, aabb[0 * N + j]);
        float ih = fminf(iymx, aabb[3 * N + j]) - fmaxf(iymn, aabb[2 * N + j]);
        if (iw > 0.0f && ih > 0.0f) {
            float jaf = aabb[4 * N + j];
            float ub = fminf(iw * ih, fminf(iaf, jaf));
            if (1.699f * ub >= 0.699f * (iaf + jaf)) {
                int p = atomicAdd(&cnt, 1);
                cand[p] = (unsigned short)j;
            }
        }
    }
    __syncthreads();

    int n = cnt;
    if (n) {
        double px[4], py[4];
#pragma unroll
        for (int k = 0; k < 4; ++k) {
            px[k] = cor[i * 8 + k * 2 + 0];
            py[k] = cor[i * 8 + k * 2 + 1];
        }
        double ai = areas[i];
        for (int k = t; k < n; k += 256) {
            int j = (int)cand[k];
            if (exact_suppress2(px, py, ai, cor, areas, j))
                atomicOr(&lmask32[j >> 5], 1u << (j & 31));
        }
    }
    __syncthreads();

    if (t < 32) {
        unsigned long long wv = ((unsigned long long)lmask32[2 * t + 1] << 32) |
                                (unsigned long long)lmask32[2 * t];
        mask[(size_t)i * 32 + t] = wv;
    }
    if (t == 0) {
        int total = 0, nf = 0;
        unsigned short tg[6] = {0, 0, 0, 0, 0, 0};
        for (int wgi = 0; wgi < 64; ++wgi) {
            unsigned int v = lmask32[wgi];
            total += __popc(v);
            while (v && nf < 6) {
                int b = __ffs(v) - 1;
                v &= v - 1u;
                tg[nf++] = (unsigned short)(wgi * 32 + b);
            }
        }
        unsigned long long i0 =
            (unsigned long long)(unsigned short)total |
            ((unsigned long long)tg[0] << 16) |
            ((unsigned long long)tg[1] << 32) |
            ((unsigned long long)tg[2] << 48);
        unsigned long long i1 = (unsigned long long)tg[3] |
                                ((unsigned long long)tg[4] << 16) |
                                ((unsigned long long)tg[5] << 32);
        rowinfo[2 * i] = i0;
        rowinfo[2 * i + 1] = i1;
    }
}

// ---------------------------------------------------------------------------
// Kernel C: edge-list greedy sweep, one wave, NO global loads on the serial
// chain.  All rowinfo preloaded into distributed VGPRs (lane l holds rows
// c*64+l).  Lane l (l<32) owns 'removed' word l.  Per chunk: ballot of
// count!=0 -> uniform 'bits'; loop bb = todo & ~dm: the lowest such row is
// provably KEPT; apply its <=6 inline targets via scalar-broadcast bit-ORs
// (count>6: one mask-row load fallback, rare); refresh dm via readlane.
// Requires N <= 2048 (harness: N=2000); mask stride fixed at 32 words.
// ---------------------------------------------------------------------------
__global__ __launch_bounds__(64, 1) void greedy_kernel(
    const unsigned long long* __restrict__ mask,
    const unsigned long long* __restrict__ rowinfo, int* __restrict__ out,
    int N, int topn) {
    constexpr int WORDS = 32;
    int lane = threadIdx.x;
    unsigned long long removed = 0ULL;

    // preload all rowinfo: lane l <- rows c*64+l (coalesced 16B/lane)
    unsigned long long ri0[WORDS], ri1[WORDS];
    const ulonglong2* rv = (const ulonglong2*)rowinfo;
#pragma unroll
    for (int c = 0; c < WORDS; ++c) {
        int r = c * 64 + lane;
        if (r < N) {
            ulonglong2 v = rv[r];
            ri0[c] = v.x;
            ri1[c] = v.y;
        } else {
            ri0[c] = 0ULL;
            ri1[c] = 0ULL;
        }
    }

#pragma unroll
    for (int c = 0; c < WORDS; ++c) {
        unsigned long long bits =
            __ballot(((ri0[c] & 0xffffULL) != 0ULL) && (c * 64 + lane < N));
        if (!bits) continue;
        unsigned long long dm = readlane64(removed, c);
        unsigned long long todo = bits;
        for (;;) {
            unsigned long long bb = todo & ~dm;
            if (!bb) break;
            int b = __builtin_amdgcn_readfirstlane(__ffsll(bb) - 1);
            todo &= ~(1ULL << b);
            // row r = c*64+b is KEPT; apply its suppression targets
            unsigned long long i0 = readlane64(ri0[c], b);
            int cnt = (int)(i0 & 0xffffULL);
            {
                int t0 = (int)((i0 >> 16) & 0xffffULL);
                if (lane == (t0 >> 6)) removed |= 1ULL << (t0 & 63);
            }
            if (cnt >= 2) {
                int t1 = (int)((i0 >> 32) & 0xffffULL);
                if (lane == (t1 >> 6)) removed |= 1ULL << (t1 & 63);
            }
            if (cnt >= 3) {
                int t2 = (int)((i0 >> 48) & 0xffffULL);
                if (lane == (t2 >> 6)) removed |= 1ULL << (t2 & 63);
            }
            if (cnt >= 4) {
                if (cnt <= 6) {
                    unsigned long long i1 = readlane64(ri1[c], b);
                    int t3 = (int)(i1 & 0xffffULL);
                    if (lane == (t3 >> 6)) removed |= 1ULL << (t3 & 63);
                    if (cnt >= 5) {
                        int t4 = (int)((i1 >> 16) & 0xffffULL);
                        if (lane == (t4 >> 6)) removed |= 1ULL << (t4 & 63);
                    }
                    if (cnt >= 6) {
                        int t5 = (int)((i1 >> 32) & 0xffffULL);
                        if (lane == (t5 >> 6)) removed |= 1ULL << (t5 & 63);
                    }
                } else {
                    // rare: >6 targets -> OR in the full mask row
                    int r = c * 64 + b;
                    removed |= mask[(size_t)r * WORDS + (lane & 31)];
                }
            }
            dm = readlane64(removed, c);
        }
    }

    // keep mask per lane-owned word, clipped to N bits
    unsigned long long keepw = 0ULL;
    if (lane < WORDS) {
        keepw = ~removed;
        int base = lane * 64;
        int valid = N - base;
        if (valid <= 0)
            keepw = 0ULL;
        else if (valid < 64)
            keepw &= ((1ULL << valid) - 1ULL);
    }

    // exclusive prefix of popcounts across lanes
    int pc = __popcll(keepw);
    int scan = pc;
#pragma unroll
    for (int off = 1; off < 64; off <<= 1) {
        int v = __shfl_up(scan, off);
        if (lane >= off) scan += v;
    }
    int base_out = scan - pc;
    int total = __shfl(scan, WORDS - 1);

    // emit kept indices
    if (lane < WORDS) {
        int pos = base_out;
        unsigned long long w = keepw;
        while (w) {
            int b = __ffsll(w) - 1;
            w &= w - 1ULL;
            if (pos < topn) out[pos] = lane * 64 + b;
            ++pos;
        }
    }
    // pad tail with -1
    for (int k = (total < topn ? total : topn) + lane; k < topn; k += 64)
        out[k] = -1;
}

// ---------------------------------------------------------------------------
extern "C" void kernel_launch(void* const* d_in, const int* in_sizes, int n_in,
                              void* d_out, int out_size, void* d_ws,
                              size_t ws_size, hipStream_t stream) {
    const float* boxes = (const float*)d_in[0];
    int N = in_sizes[0] / 5;  // 2000 (kernel C requires N <= 2048)
    int topn = out_size;      // 1000

    char* ws = (char*)d_ws;
    size_t off = 0;
    double* cor = (double*)(ws + off);   off += (size_t)N * 8 * 8;      // 128000
    double* areas = (double*)(ws + off); off += (size_t)N * 8;          // 16000
    unsigned long long* mask =
        (unsigned long long*)(ws + off); off += (size_t)N * 32 * 8;     // 512000
    float* aabb = (float*)(ws + off);    off += (size_t)N * 5 * 4;      // 40000
    unsigned long long* rowinfo =
        (unsigned long long*)(ws + off); off += (size_t)N * 16;         // 32000

    corners_kernel<<<(N + 255) / 256, 256, 0, stream>>>(boxes, cor, areas,
                                                        aabb, N);
    iou_fused_kernel<<<N, 256, 0, stream>>>(aabb, cor, areas, mask, rowinfo,
                                            N);
    greedy_kernel<<<1, 64, 0, stream>>>(mask, rowinfo, (int*)d_out, N, topn);
}

// Round 8
// 86.956 us; speedup vs baseline: 1.3040x; 1.0701x over previous
//
#include <hip/hip_runtime.h>

#define NMS_TH 0.7

__device__ __forceinline__ unsigned long long readlane64(unsigned long long x,
                                                         int l) {
    unsigned int lo = __builtin_amdgcn_readlane((unsigned int)x, l);
    unsigned int hi = __builtin_amdgcn_readlane((unsigned int)(x >> 32), l);
    return ((unsigned long long)hi << 32) | lo;
}

// ---------------------------------------------------------------------------
// Kernel A: fp64 corners + fp32 corners + fp64 areas + packed fp32 AABB.
// aabb4[i] = {xmin, xmax, ymin, ymax}; areaf[i] = w*h (fp32).
// ---------------------------------------------------------------------------
__global__ void corners_kernel(const float* __restrict__ boxes,
                               double* __restrict__ cor,    // N*8 fp64
                               float* __restrict__ cor32,   // N*8 fp32
                               double* __restrict__ areas,  // N fp64
                               float4* __restrict__ aabb4,  // N
                               float* __restrict__ areaf,   // N fp32
                               int N) {
    int i = blockIdx.x * blockDim.x + threadIdx.x;
    if (i >= N) return;
    double xc = boxes[i * 5 + 0];
    double yc = boxes[i * 5 + 1];
    double w  = boxes[i * 5 + 2];
    double h  = boxes[i * 5 + 3];
    double t  = boxes[i * 5 + 4];
    double th = t * 0.017453292519943295;  // pi/180
    double c = cos(th), s = sin(th);
    const double lx[4] = {0.5, -0.5, -0.5, 0.5};
    const double ly[4] = {0.5, 0.5, -0.5, -0.5};
    double xmn = 1e30, xmx = -1e30, ymn = 1e30, ymx = -1e30;
#pragma unroll
    for (int k = 0; k < 4; ++k) {
        double x = xc + lx[k] * w * c - ly[k] * h * s;
        double y = yc + lx[k] * w * s + ly[k] * h * c;
        cor[i * 8 + k * 2 + 0] = x;
        cor[i * 8 + k * 2 + 1] = y;
        cor32[i * 8 + k * 2 + 0] = (float)x;
        cor32[i * 8 + k * 2 + 1] = (float)y;
        xmn = fmin(xmn, x); xmx = fmax(xmx, x);
        ymn = fmin(ymn, y); ymx = fmax(ymx, y);
    }
    areas[i] = w * h;
    aabb4[i] = make_float4((float)xmn, (float)xmx, (float)ymn, (float)ymx);
    areaf[i] = (float)(w * h);
}

// ---------------------------------------------------------------------------
// Convex-quad intersection area via Green's theorem — fp64 exact version.
// ---------------------------------------------------------------------------
__device__ __forceinline__ double clip_sum(const double* __restrict__ px,
                                           const double* __restrict__ py,
                                           const double* __restrict__ qx,
                                           const double* __restrict__ qy) {
    double acc = 0.0;
#pragma unroll
    for (int e = 0; e < 4; ++e) {
        double x0 = px[e], y0 = py[e];
        double x1 = px[(e + 1) & 3], y1 = py[(e + 1) & 3];
        double dx = x1 - x0, dy = y1 - y0;
        double t0 = 0.0, t1 = 1.0;
        bool empty = false;
#pragma unroll
        for (int f = 0; f < 4; ++f) {
            double ex0 = qx[f], ey0 = qy[f];
            double ex1 = qx[(f + 1) & 3], ey1 = qy[(f + 1) & 3];
            double edx = ex1 - ex0, edy = ey1 - ey0;
            double f0 = edx * (y0 - ey0) - edy * (x0 - ex0);
            double f1 = edx * (y1 - ey0) - edy * (x1 - ex0);
            double df = f1 - f0;
            if (df > 0.0) {
                t0 = fmax(t0, -f0 / df);
            } else if (df < 0.0) {
                t1 = fmin(t1, -f0 / df);
            } else if (f0 < 0.0) {
                empty = true;
            }
        }
        if (!empty && t0 < t1) {
            double ax = x0 + t0 * dx, ay = y0 + t0 * dy;
            double bx = x0 + t1 * dx, by = y0 + t1 * dy;
            acc += ax * by - bx * ay;
        }
    }
    return acc;
}

__device__ __forceinline__ bool exact_suppress64(const double* __restrict__ cor,
                                                 const double* __restrict__ areas,
                                                 int i, int j) {
    double px[4], py[4], qx[4], qy[4];
#pragma unroll
    for (int k = 0; k < 4; ++k) {
        px[k] = cor[i * 8 + k * 2 + 0];
        py[k] = cor[i * 8 + k * 2 + 1];
        qx[k] = cor[j * 8 + k * 2 + 0];
        qy[k] = cor[j * 8 + k * 2 + 1];
    }
    double inter = 0.5 * (clip_sum(px, py, qx, qy) + clip_sum(qx, qy, px, py));
    inter = fmax(inter, 0.0);
    double uni = areas[i] + areas[j] - inter;
    double iou = inter / fmax(uni, 1e-8);
    return iou > NMS_TH;
}

// ---------------------------------------------------------------------------
// fp32 fast-path clip: hardware rcp for the t-divides (~1 ulp, well inside
// the decision guard band).
// ---------------------------------------------------------------------------
__device__ __forceinline__ float clip_sum_f32(const float* __restrict__ px,
                                              const float* __restrict__ py,
                                              const float* __restrict__ qx,
                                              const float* __restrict__ qy) {
    float acc = 0.0f;
#pragma unroll
    for (int e = 0; e < 4; ++e) {
        float x0 = px[e], y0 = py[e];
        float x1 = px[(e + 1) & 3], y1 = py[(e + 1) & 3];
        float dx = x1 - x0, dy = y1 - y0;
        float t0 = 0.0f, t1 = 1.0f;
        bool empty = false;
#pragma unroll
        for (int f = 0; f < 4; ++f) {
            float ex0 = qx[f], ey0 = qy[f];
            float ex1 = qx[(f + 1) & 3], ey1 = qy[(f + 1) & 3];
            float edx = ex1 - ex0, edy = ey1 - ey0;
            float f0 = edx * (y0 - ey0) - edy * (x0 - ex0);
            float f1 = edx * (y1 - ey0) - edy * (x1 - ex0);
            float df = f1 - f0;
            if (df > 0.0f) {
                float tt = -f0 * __builtin_amdgcn_rcpf(df);
                t0 = fmaxf(t0, tt);
            } else if (df < 0.0f) {
                float tt = -f0 * __builtin_amdgcn_rcpf(df);
                t1 = fminf(t1, tt);
            } else if (f0 < 0.0f) {
                empty = true;
            }
        }
        if (!empty && t0 < t1) {
            float ax = x0 + t0 * dx, ay = y0 + t0 * dy;
            float bx = x0 + t1 * dx, by = y0 + t1 * dy;
            acc += ax * by - bx * ay;
        }
    }
    return acc;
}

// ---------------------------------------------------------------------------
// Kernel B (fused): block = row i, 256 threads.
// Phase 1: packed-AABB upper-bound filter (exact-safe guard band) -> LDS
//   candidate list.
// Phase 2: fp32 clip decides unless |iou32-0.7| <= 5e-3, then fp64 exact.
// Epilogue: 32-word mask row + rowinfo (count + first 6 targets inline).
// ---------------------------------------------------------------------------
__global__ __launch_bounds__(256) void iou_fused_kernel(
    const float4* __restrict__ aabb4, const float* __restrict__ areaf,
    const float* __restrict__ cor32, const double* __restrict__ cor,
    const double* __restrict__ areas, unsigned long long* __restrict__ mask,
    unsigned long long* __restrict__ rowinfo, int N) {
    __shared__ unsigned short cand[2048];
    __shared__ unsigned int lmask32[64];
    __shared__ int cnt;
    __shared__ unsigned long long nzwords;

    int i = blockIdx.x;
    int t = threadIdx.x;
    if (t == 0) cnt = 0;
    if (t < 64) lmask32[t] = 0u;
    __syncthreads();

    float4 bi = aabb4[i];
    float iaf = areaf[i];

    int j0 = (((i + 1) >> 8) << 8) + t;  // first 256-block containing i+1
    for (int j = j0; j < N; j += 256) {
        if (j <= i) continue;
        float4 bj = aabb4[j];
        float iw = fminf(bi.y, bj.y) - fmaxf(bi.x, bj.x);
        float ih = fminf(bi.w, bj.w) - fmaxf(bi.z, bj.z);
        if (iw > 0.0f && ih > 0.0f) {
            float jaf = areaf[j];
            float ub = fminf(iw * ih, fminf(iaf, jaf));
            if (1.699f * ub >= 0.699f * (iaf + jaf)) {
                int p = atomicAdd(&cnt, 1);
                cand[p] = (unsigned short)j;
            }
        }
    }
    __syncthreads();

    int n = cnt;
    if (n) {
        float px[4], py[4];
#pragma unroll
        for (int k = 0; k < 4; ++k) {
            px[k] = cor32[i * 8 + k * 2 + 0];
            py[k] = cor32[i * 8 + k * 2 + 1];
        }
        float ai = (float)iaf;
        for (int k = t; k < n; k += 256) {
            int j = (int)cand[k];
            float qx[4], qy[4];
#pragma unroll
            for (int kk = 0; kk < 4; ++kk) {
                qx[kk] = cor32[j * 8 + kk * 2 + 0];
                qy[kk] = cor32[j * 8 + kk * 2 + 1];
            }
            float inter =
                0.5f * (clip_sum_f32(px, py, qx, qy) + clip_sum_f32(qx, qy, px, py));
            inter = fmaxf(inter, 0.0f);
            float uni = ai + areaf[j] - inter;
            float iou = inter / fmaxf(uni, 1e-8f);
            bool sup;
            if (fabsf(iou - 0.7f) > 5e-3f)
                sup = iou > 0.7f;             // fp32 decision, outside band
            else
                sup = exact_suppress64(cor, areas, i, j);  // rare fallback
            if (sup) atomicOr(&lmask32[j >> 5], 1u << (j & 31));
        }
    }
    __syncthreads();

    // nonzero-word bitmap (wave 0) for a sparse epilogue scan
    if (t < 64) {
        unsigned long long bal = __ballot(lmask32[t] != 0u);
        if (t == 0) nzwords = bal;
    }
    if (t < 32) {
        unsigned long long wv = ((unsigned long long)lmask32[2 * t + 1] << 32) |
                                (unsigned long long)lmask32[2 * t];
        mask[(size_t)i * 32 + t] = wv;
    }
    __syncthreads();
    if (t == 0) {
        int total = 0, nf = 0;
        unsigned short tg[6] = {0, 0, 0, 0, 0, 0};
        unsigned long long nz = nzwords;
        while (nz) {
            int wgi = __ffsll(nz) - 1;
            nz &= nz - 1ULL;
            unsigned int v = lmask32[wgi];
            total += __popc(v);
            while (v && nf < 6) {
                int b = __ffs(v) - 1;
                v &= v - 1u;
                tg[nf++] = (unsigned short)(wgi * 32 + b);
            }
        }
        unsigned long long i0 =
            (unsigned long long)(unsigned short)total |
            ((unsigned long long)tg[0] << 16) |
            ((unsigned long long)tg[1] << 32) |
            ((unsigned long long)tg[2] << 48);
        unsigned long long i1 = (unsigned long long)tg[3] |
                                ((unsigned long long)tg[4] << 16) |
                                ((unsigned long long)tg[5] << 32);
        rowinfo[2 * i] = i0;
        rowinfo[2 * i + 1] = i1;
    }
}

// ---------------------------------------------------------------------------
// Kernel C: edge-list greedy sweep, one wave, no global loads on the serial
// chain (rowinfo preloaded into distributed VGPRs).  Lane l (<32) owns
// 'removed' word l.  Per chunk: uniform suppressor bitmap via ballot; lowest
// unsuppressed suppressor row is provably kept; apply its <=6 inline targets
// via scalar-broadcast bit-ORs (count>6: one mask-row load, rare).
// Requires N <= 2048 (harness: N=2000); mask stride fixed at 32 words.
// ---------------------------------------------------------------------------
__global__ __launch_bounds__(64, 1) void greedy_kernel(
    const unsigned long long* __restrict__ mask,
    const unsigned long long* __restrict__ rowinfo, int* __restrict__ out,
    int N, int topn) {
    constexpr int WORDS = 32;
    int lane = threadIdx.x;
    unsigned long long removed = 0ULL;

    unsigned long long ri0[WORDS], ri1[WORDS];
    const ulonglong2* rv = (const ulonglong2*)rowinfo;
#pragma unroll
    for (int c = 0; c < WORDS; ++c) {
        int r = c * 64 + lane;
        if (r < N) {
            ulonglong2 v = rv[r];
            ri0[c] = v.x;
            ri1[c] = v.y;
        } else {
            ri0[c] = 0ULL;
            ri1[c] = 0ULL;
        }
    }

#pragma unroll
    for (int c = 0; c < WORDS; ++c) {
        unsigned long long bits =
            __ballot(((ri0[c] & 0xffffULL) != 0ULL) && (c * 64 + lane < N));
        if (!bits) continue;
        unsigned long long dm = readlane64(removed, c);
        unsigned long long todo = bits;
        for (;;) {
            unsigned long long bb = todo & ~dm;
            if (!bb) break;
            int b = __builtin_amdgcn_readfirstlane(__ffsll(bb) - 1);
            todo &= ~(1ULL << b);
            unsigned long long i0 = readlane64(ri0[c], b);
            int cnt = (int)(i0 & 0xffffULL);
            {
                int t0 = (int)((i0 >> 16) & 0xffffULL);
                if (lane == (t0 >> 6)) removed |= 1ULL << (t0 & 63);
            }
            if (cnt >= 2) {
                int t1 = (int)((i0 >> 32) & 0xffffULL);
                if (lane == (t1 >> 6)) removed |= 1ULL << (t1 & 63);
            }
            if (cnt >= 3) {
                int t2 = (int)((i0 >> 48) & 0xffffULL);
                if (lane == (t2 >> 6)) removed |= 1ULL << (t2 & 63);
            }
            if (cnt >= 4) {
                if (cnt <= 6) {
                    unsigned long long i1 = readlane64(ri1[c], b);
                    int t3 = (int)(i1 & 0xffffULL);
                    if (lane == (t3 >> 6)) removed |= 1ULL << (t3 & 63);
                    if (cnt >= 5) {
                        int t4 = (int)((i1 >> 16) & 0xffffULL);
                        if (lane == (t4 >> 6)) removed |= 1ULL << (t4 & 63);
                    }
                    if (cnt >= 6) {
                        int t5 = (int)((i1 >> 32) & 0xffffULL);
                        if (lane == (t5 >> 6)) removed |= 1ULL << (t5 & 63);
                    }
                } else {
                    int r = c * 64 + b;
                    removed |= mask[(size_t)r * WORDS + (lane & 31)];
                }
            }
            dm = readlane64(removed, c);
        }
    }

    unsigned long long keepw = 0ULL;
    if (lane < WORDS) {
        keepw = ~removed;
        int base = lane * 64;
        int valid = N - base;
        if (valid <= 0)
            keepw = 0ULL;
        else if (valid < 64)
            keepw &= ((1ULL << valid) - 1ULL);
    }

    int pc = __popcll(keepw);
    int scan = pc;
#pragma unroll
    for (int off = 1; off < 64; off <<= 1) {
        int v = __shfl_up(scan, off);
        if (lane >= off) scan += v;
    }
    int base_out = scan - pc;
    int total = __shfl(scan, WORDS - 1);

    if (lane < WORDS) {
        int pos = base_out;
        unsigned long long w = keepw;
        while (w) {
            int b = __ffsll(w) - 1;
            w &= w - 1ULL;
            if (pos < topn) out[pos] = lane * 64 + b;
            ++pos;
        }
    }
    for (int k = (total < topn ? total : topn) + lane; k < topn; k += 64)
        out[k] = -1;
}

// ---------------------------------------------------------------------------
extern "C" void kernel_launch(void* const* d_in, const int* in_sizes, int n_in,
                              void* d_out, int out_size, void* d_ws,
                              size_t ws_size, hipStream_t stream) {
    const float* boxes = (const float*)d_in[0];
    int N = in_sizes[0] / 5;  // 2000 (kernel C requires N <= 2048)
    int topn = out_size;      // 1000

    char* ws = (char*)d_ws;
    size_t off = 0;
    double* cor = (double*)(ws + off);     off += (size_t)N * 8 * 8;    // 128000
    float* cor32 = (float*)(ws + off);     off += (size_t)N * 8 * 4;    // 64000
    double* areas = (double*)(ws + off);   off += (size_t)N * 8;        // 16000
    unsigned long long* mask =
        (unsigned long long*)(ws + off);   off += (size_t)N * 32 * 8;   // 512000
    float4* aabb4 = (float4*)(ws + off);   off += (size_t)N * 16;       // 32000
    float* areaf = (float*)(ws + off);     off += (size_t)N * 4;        // 8000
    unsigned long long* rowinfo =
        (unsigned long long*)(ws + off);   off += (size_t)N * 16;       // 32000

    corners_kernel<<<(N + 255) / 256, 256, 0, stream>>>(
        boxes, cor, cor32, areas, aabb4, areaf, N);
    iou_fused_kernel<<<N, 256, 0, stream>>>(aabb4, areaf, cor32, cor, areas,
                                            mask, rowinfo, N);
    greedy_kernel<<<1, 64, 0, stream>>>(mask, rowinfo, (int*)d_out, N, topn);
}